// Round 2
// baseline (1332.519 us; speedup 1.0000x reference)
//
#include <hip/hip_runtime.h>

// ---------------------------------------------------------------------------
// TrajectoryDecoder: B=4096, F=256, H=256, M=3, T=30 (T read from device)
// out = [trajectories (B,M,T,2) fp32][mode_probs (B,M) fp32]
// R16: revert MFMA shape to R14's proven 16x16x32 (R15 showed 32x32x16 has
// IDENTICAL MFMA-busy cycles but worse latency hiding). Structural change:
// block = 32 rows x 4 waves (256 thr), wave owns TWO of R14's 32-col groups.
// LDS 81,152B (h0 dbuf kept; cwp0/1 stored bf16) -> 2 blocks/CU: two
// independent barrier domains overlap each other's stalls (kernel is ~66%
// stall per R14 counters), and all 256 CUs are active (R14: 192 + 64 idle).
// Grid 384, bijective XCD-lane mapping (<=2 modes per XCD for L2 locality).
// Spill-free discipline kept: merged rz+n (128 acc regs), #pragma unroll 1
// K-loops, named running pointers.
// ---------------------------------------------------------------------------

typedef __attribute__((ext_vector_type(8))) short bf16x8;
typedef __attribute__((ext_vector_type(4))) float f32x4;

__device__ __forceinline__ short f2bf(float f) {
    unsigned u = __builtin_bit_cast(unsigned, f);
    unsigned r = (u + 0x7fffu + ((u >> 16) & 1u)) >> 16;
    return (short)r;
}
__device__ __forceinline__ float bf2f(short s) {
    unsigned u = ((unsigned)(unsigned short)s) << 16;
    return __builtin_bit_cast(float, u);
}
__device__ __forceinline__ float fast_sigmoid(float x) {
    x = fminf(fmaxf(x, -30.f), 30.f);
    float e = __builtin_amdgcn_exp2f(x * -1.442695041f);
    return __builtin_amdgcn_rcpf(1.f + e);
}
__device__ __forceinline__ float fast_tanh(float x) {
    x = fminf(fmaxf(x, -15.f), 15.f);
    float e = __builtin_amdgcn_exp2f(x * -2.885390082f);
    return (1.f - e) * __builtin_amdgcn_rcpf(1.f + e);
}

// ---------------------------------------------------------------------------
// Weight prep: fp32 -> bf16, B-fragment consumption order (R14 layout).
// Regions (1KB blocks):
//   P0  [0,1152):    w_hh0 per (m,w8): 48 = [rz: ks*4+t (32)][n: 32+ks*2+nt]
//   P1  [1152,3456): per (m,w8): 96 = [rz: half*32+ks*4+t (64)]
//                                     [xn: 64+ks*2+nt][hn: 80+ks*2+nt]
//   PC  [3456,4608): w_ih0[:,2:258] per (m,w8): 48 = [ks*6+t6]
// ---------------------------------------------------------------------------
__global__ void prep_kernel(const float* __restrict__ w_ih0,
                            const float* __restrict__ w_hh0,
                            const float* __restrict__ w_ih1,
                            const float* __restrict__ w_hh1,
                            short* __restrict__ ws) {
    int bid = blockIdx.x;
    int L = threadIdx.x;
    const float* src;
    int srcRowLen, colBase, m, w, ks, t;
    if (bid < 1152) {
        int idx = bid, mw = idx / 48, blk = idx % 48;
        m = mw / 8; w = mw % 8;
        if (blk < 32) { ks = blk >> 2; t = blk & 3; }
        else { int q = blk - 32; ks = q >> 1; t = 4 + (q & 1); }
        src = w_hh0 + (size_t)m * 768 * 256; srcRowLen = 256; colBase = 0;
    } else if (bid < 3456) {
        int idx = bid - 1152, mw = idx / 96, blk = idx % 96;
        m = mw / 8; w = mw % 8;
        int half;
        if (blk < 64) { half = blk >> 5; ks = (blk >> 2) & 7; t = blk & 3; }
        else { int q = blk - 64; half = q >> 4; ks = (q >> 1) & 7; t = 4 + (q & 1); }
        src = (half ? w_hh1 : w_ih1) + (size_t)m * 768 * 256;
        srcRowLen = 256; colBase = 0;
    } else {
        int idx = bid - 3456, mw = idx / 48, blk = idx % 48;
        m = mw / 8; w = mw % 8; ks = blk / 6; t = blk % 6;
        src = w_ih0 + (size_t)m * 768 * 258; srcRowLen = 258; colBase = 2;
    }
    int row = (t >> 1) * 256 + 32 * w + (t & 1) * 16 + (L & 15);
    int col0 = colBase + ks * 32 + (L >> 4) * 8;
    short* dst = ws + (size_t)bid * 512 + L * 8;
    const float* s = src + (size_t)row * srcRowLen + col0;
#pragma unroll
    for (int j = 0; j < 8; ++j) dst[j] = f2bf(s[j]);
}

// ---------------------------------------------------------------------------
// Mode-probability MLP
// ---------------------------------------------------------------------------
__global__ __launch_bounds__(256) void modeprobs_kernel(
    const float* __restrict__ ctx, const float* __restrict__ w1,
    const float* __restrict__ b1, const float* __restrict__ w2,
    const float* __restrict__ b2, float* __restrict__ out,
    long probs_off) {
    __shared__ float w1s[64 * 256];
    int tid = threadIdx.x;
    int j = tid & 63;
    int rsub = tid >> 6;
#pragma unroll
    for (int i = 0; i < 64; ++i) w1s[tid + i * 256] = w1[tid + i * 256];
    float b1v = b1[j];
    float w2v0 = w2[j], w2v1 = w2[64 + j], w2v2 = w2[128 + j];
    float b20 = b2[0], b21 = b2[1], b22 = b2[2];
    __syncthreads();
    for (int c = 0; c < 16; ++c) {
        int brow = blockIdx.x * 64 + c * 4 + rsub;
        const float* crow = ctx + (size_t)brow * 256;
        float accv = b1v;
#pragma unroll 8
        for (int k = 0; k < 256; ++k) {
            int kk = (k + j) & 255;
            accv += w1s[j * 256 + kk] * crow[kk];
        }
        float h = fmaxf(accv, 0.f);
        float l0 = h * w2v0, l1 = h * w2v1, l2 = h * w2v2;
#pragma unroll
        for (int s = 1; s < 64; s <<= 1) {
            l0 += __shfl_xor(l0, s);
            l1 += __shfl_xor(l1, s);
            l2 += __shfl_xor(l2, s);
        }
        if (j == 0) {
            l0 += b20; l1 += b21; l2 += b22;
            float mx = fmaxf(l0, fmaxf(l1, l2));
            float e0 = __builtin_amdgcn_exp2f((l0 - mx) * 1.442695041f);
            float e1 = __builtin_amdgcn_exp2f((l1 - mx) * 1.442695041f);
            float e2 = __builtin_amdgcn_exp2f((l2 - mx) * 1.442695041f);
            float inv = 1.f / (e0 + e1 + e2);
            out[probs_off + (size_t)brow * 3 + 0] = e0 * inv;
            out[probs_off + (size_t)brow * 3 + 1] = e1 * inv;
            out[probs_off + (size_t)brow * 3 + 2] = e2 * inv;
        }
    }
}

// ---------------------------------------------------------------------------
// Persistent GRU decoder. Block = 32 batch rows x 1 mode; 256 threads
// (4 waves; wave w owns col-groups wg=2w,2w+1, i.e. cols [64w,64w+64) per
// gate). 16x16x32 MFMA, R14 fragment layout. h0 double-buffered: 4 barriers.
// 2 blocks/CU (LDS 81,152B) -> two independent barrier domains per CU.
// ---------------------------------------------------------------------------
__global__ __launch_bounds__(256, 2) void decoder_kernel(
    const float* __restrict__ context,
    const float* __restrict__ w_ih0_f,   // (3,768,258): pos-weight cols 0..1
    const float* __restrict__ b_ih0, const float* __restrict__ b_hh0,
    const float* __restrict__ b_ih1, const float* __restrict__ b_hh1,
    const float* __restrict__ out_w, const float* __restrict__ out_b,
    const short* __restrict__ ws, float* __restrict__ out,
    const int* __restrict__ pT, int tilesPerMode, int nwork) {
    __shared__ short ctxS[32 * 264];   // read-only after init
    __shared__ short h0a[32 * 264], h0b[32 * 264];  // double-buffered h0
    __shared__ short h1s[32 * 264];
    __shared__ float posD[64];
    __shared__ float owl[512];
    __shared__ short cwp0h[768], cwp1h[768];  // w_ih0[:,0], w_ih0[:,1] (bf16)
    __shared__ float cbA[512];              // L0 rz: b_ih0+b_hh0
    __shared__ float cbXn[256];             // L0 n:  b_ih0
    __shared__ float cbh0n[256];            // L0 n:  b_hh0
    __shared__ float cb1A[512];             // L1 rz: b_ih1+b_hh1
    __shared__ float cb1X[256];             // L1 n:  b_ih1
    __shared__ float cb1H[256];             // L1 n:  b_hh1

    // Bijective lane-balanced XCD mapping: lane8 gets a contiguous work chunk
    // (same/neighbor modes -> per-XCD L2 holds <=2 modes' weights).
    const int lane8 = blockIdx.x & 7, slot = blockIdx.x >> 3;
    const int q = nwork >> 3, r8 = nwork & 7;
    int start, cnt;
    if (lane8 < r8) { cnt = q + 1; start = lane8 * (q + 1); }
    else            { cnt = q;     start = r8 * (q + 1) + (lane8 - r8) * q; }
    if (slot >= cnt) return;
    const int work = start + slot;
    const int m = work / tilesPerMode;
    const int b0 = (work - m * tilesPerMode) * 32;

    const int T = *pT;
    const int tid = threadIdx.x;
    const int lane = tid & 63, w = tid >> 6;       // w in [0,4)
    const int lr = lane & 15, quad = lane >> 4;

    if (tid < 64) posD[tid] = 0.f;
    owl[tid] = out_w[m * 512 + tid];
    owl[256 + tid] = out_w[m * 512 + 256 + tid];
    cbA[tid] = b_ih0[m * 768 + tid] + b_hh0[m * 768 + tid];
    cbA[256 + tid] = b_ih0[m * 768 + 256 + tid] + b_hh0[m * 768 + 256 + tid];
    cb1A[tid] = b_ih1[m * 768 + tid] + b_hh1[m * 768 + tid];
    cb1A[256 + tid] = b_ih1[m * 768 + 256 + tid] + b_hh1[m * 768 + 256 + tid];
    cbXn[tid] = b_ih0[m * 768 + 512 + tid];
    cbh0n[tid] = b_hh0[m * 768 + 512 + tid];
    cb1X[tid] = b_ih1[m * 768 + 512 + tid];
    cb1H[tid] = b_hh1[m * 768 + 512 + tid];
    for (int cc = tid; cc < 768; cc += 256) {
        cwp0h[cc] = f2bf(w_ih0_f[((size_t)m * 768 + cc) * 258 + 0]);
        cwp1h[cc] = f2bf(w_ih0_f[((size_t)m * 768 + cc) * 258 + 1]);
    }
#pragma unroll
    for (int i = 0; i < 32; ++i) {
        int idx = tid + i * 256;
        int rr = idx >> 8, k = idx & 255;
        short v = f2bf(context[(size_t)(b0 + rr) * 256 + k]);
        ctxS[rr * 264 + k] = v;
        h0a[rr * 264 + k] = v;
        h1s[rr * 264 + k] = v;
    }
    const float ob0v = out_b[m * 2 + 0], ob1v = out_b[m * 2 + 1];

    // Weight region bases per col-group (wg = 2w+g2), R14 layout.
    const short* p0B[2];  // w_hh0
    const short* p1B[2];  // layer1 block
    const short* pcB[2];  // w_ih0 ctx cols
#pragma unroll
    for (int g2 = 0; g2 < 2; ++g2) {
        const int wg = 2 * w + g2;
        p0B[g2] = ws + ((size_t)(m * 8 + wg) * 48) * 512 + lane * 8;
        p1B[g2] = ws + (size_t)1152 * 512 + ((size_t)(m * 8 + wg) * 96) * 512 + lane * 8;
        pcB[g2] = ws + (size_t)3456 * 512 + ((size_t)(m * 8 + wg) * 48) * 512 + lane * 8;
    }

    __syncthreads();

    float cum0 = 0.f, cum1 = 0.f;

    for (int st = 0; st < T; ++st) {
        const short* h0c = (st & 1) ? h0b : h0a;   // current h0
        short* h0n_ = (st & 1) ? h0a : h0b;        // next h0 (no WAR hazard)

        // ======== layer 0 (merged rz+n, unroll-1 K-loop) ========
        {
            f32x4 arz[2][4][2], axn[2][2][2], ahn[2][2][2];
            float px[2][4], py[2][4];
#pragma unroll
            for (int rt = 0; rt < 2; ++rt)
#pragma unroll
                for (int rr = 0; rr < 4; ++rr) {
                    int row = rt * 16 + quad * 4 + rr;
                    px[rt][rr] = posD[row * 2];
                    py[rt][rr] = posD[row * 2 + 1];
                }
#pragma unroll
            for (int g2 = 0; g2 < 2; ++g2) {
                const int cbase = 32 * (2 * w + g2) + lr;
#pragma unroll
                for (int t = 0; t < 4; ++t) {
                    const int c = (t >> 1) * 256 + cbase + (t & 1) * 16;
                    const float bb = cbA[c];
                    const float w0 = bf2f(cwp0h[c]), w1 = bf2f(cwp1h[c]);
#pragma unroll
                    for (int rt = 0; rt < 2; ++rt)
#pragma unroll
                        for (int rr = 0; rr < 4; ++rr)
                            arz[g2][t][rt][rr] =
                                bb + px[rt][rr] * w0 + py[rt][rr] * w1;
                }
#pragma unroll
                for (int nt = 0; nt < 2; ++nt) {
                    const int cn = cbase + nt * 16;
                    const float bx = cbXn[cn], bh = cbh0n[cn];
                    const float w0 = bf2f(cwp0h[512 + cn]);
                    const float w1 = bf2f(cwp1h[512 + cn]);
#pragma unroll
                    for (int rt = 0; rt < 2; ++rt)
#pragma unroll
                        for (int rr = 0; rr < 4; ++rr) {
                            axn[g2][nt][rt][rr] =
                                bx + px[rt][rr] * w0 + py[rt][rr] * w1;
                            ahn[g2][nt][rt][rr] = bh;
                        }
                }
            }
            const short* bpc0 = pcB[0];
            const short* bpc1 = pcB[1];
            const short* brz0 = p0B[0];
            const short* brz1 = p0B[1];
            const short* bn0 = p0B[0] + 32 * 512;
            const short* bn1 = p0B[1] + 32 * 512;
#pragma unroll 1
            for (int ks = 0; ks < 8; ++ks) {
                bf16x8 ac[2], ah[2];
#pragma unroll
                for (int rt = 0; rt < 2; ++rt) {
                    ac[rt] = *reinterpret_cast<const bf16x8*>(
                        ctxS + (rt * 16 + lr) * 264 + ks * 32 + quad * 8);
                    ah[rt] = *reinterpret_cast<const bf16x8*>(
                        h0c + (rt * 16 + lr) * 264 + ks * 32 + quad * 8);
                }
#pragma unroll
                for (int g2 = 0; g2 < 2; ++g2) {
                    const short* bpc = g2 ? bpc1 : bpc0;
                    const short* brz = g2 ? brz1 : brz0;
                    const short* bn = g2 ? bn1 : bn0;
#pragma unroll
                    for (int t = 0; t < 4; ++t) {
                        bf16x8 b = *reinterpret_cast<const bf16x8*>(bpc + t * 512);
#pragma unroll
                        for (int rt = 0; rt < 2; ++rt)
                            arz[g2][t][rt] = __builtin_amdgcn_mfma_f32_16x16x32_bf16(
                                ac[rt], b, arz[g2][t][rt], 0, 0, 0);
                    }
#pragma unroll
                    for (int nt = 0; nt < 2; ++nt) {
                        bf16x8 b = *reinterpret_cast<const bf16x8*>(bpc + (4 + nt) * 512);
#pragma unroll
                        for (int rt = 0; rt < 2; ++rt)
                            axn[g2][nt][rt] = __builtin_amdgcn_mfma_f32_16x16x32_bf16(
                                ac[rt], b, axn[g2][nt][rt], 0, 0, 0);
                    }
#pragma unroll
                    for (int t = 0; t < 4; ++t) {
                        bf16x8 b = *reinterpret_cast<const bf16x8*>(brz + t * 512);
#pragma unroll
                        for (int rt = 0; rt < 2; ++rt)
                            arz[g2][t][rt] = __builtin_amdgcn_mfma_f32_16x16x32_bf16(
                                ah[rt], b, arz[g2][t][rt], 0, 0, 0);
                    }
#pragma unroll
                    for (int nt = 0; nt < 2; ++nt) {
                        bf16x8 b = *reinterpret_cast<const bf16x8*>(bn + nt * 512);
#pragma unroll
                        for (int rt = 0; rt < 2; ++rt)
                            ahn[g2][nt][rt] = __builtin_amdgcn_mfma_f32_16x16x32_bf16(
                                ah[rt], b, ahn[g2][nt][rt], 0, 0, 0);
                    }
                }
                bpc0 += 6 * 512; bpc1 += 6 * 512;
                brz0 += 4 * 512; brz1 += 4 * 512;
                bn0 += 2 * 512;  bn1 += 2 * 512;
            }
            // no barrier: epilogue writes h0n_ (other buffer), no WAR hazard
#pragma unroll
            for (int g2 = 0; g2 < 2; ++g2)
#pragma unroll
                for (int nt = 0; nt < 2; ++nt) {
                    const int col = 32 * (2 * w + g2) + nt * 16 + lr;
#pragma unroll
                    for (int rt = 0; rt < 2; ++rt)
#pragma unroll
                        for (int rr = 0; rr < 4; ++rr) {
                            int row = rt * 16 + quad * 4 + rr;
                            float rg = fast_sigmoid(arz[g2][nt][rt][rr]);
                            float zg = fast_sigmoid(arz[g2][2 + nt][rt][rr]);
                            float ng = fast_tanh(axn[g2][nt][rt][rr] +
                                                 rg * ahn[g2][nt][rt][rr]);
                            float hold = bf2f(h0c[row * 264 + col]);
                            h0n_[row * 264 + col] =
                                f2bf((1.f - zg) * ng + zg * hold);
                        }
                }
        }
        __syncthreads();  // B1: h0' visible

        // ======== layer 1 (merged rz+n, unroll-1 K-loop) ========
        {
            f32x4 arz[2][4][2], axn[2][2][2], ahn[2][2][2];
#pragma unroll
            for (int g2 = 0; g2 < 2; ++g2) {
                const int cbase = 32 * (2 * w + g2) + lr;
#pragma unroll
                for (int t = 0; t < 4; ++t) {
                    const int c = (t >> 1) * 256 + cbase + (t & 1) * 16;
                    const float bb = cb1A[c];
#pragma unroll
                    for (int rt = 0; rt < 2; ++rt)
#pragma unroll
                        for (int rr = 0; rr < 4; ++rr)
                            arz[g2][t][rt][rr] = bb;
                }
#pragma unroll
                for (int nt = 0; nt < 2; ++nt) {
                    const int cn = cbase + nt * 16;
                    const float bx = cb1X[cn], bh = cb1H[cn];
#pragma unroll
                    for (int rt = 0; rt < 2; ++rt)
#pragma unroll
                        for (int rr = 0; rr < 4; ++rr) {
                            axn[g2][nt][rt][rr] = bx;
                            ahn[g2][nt][rt][rr] = bh;
                        }
                }
            }
            const short* bq00 = p1B[0];
            const short* bq01 = p1B[1];
            const short* bq10 = p1B[0] + 32 * 512;
            const short* bq11 = p1B[1] + 32 * 512;
            const short* bx0 = p1B[0] + 64 * 512;
            const short* bx1 = p1B[1] + 64 * 512;
            const short* bh0 = p1B[0] + 80 * 512;
            const short* bh1 = p1B[1] + 80 * 512;
#pragma unroll 1
            for (int ks = 0; ks < 8; ++ks) {
                bf16x8 a0[2], a1[2];
#pragma unroll
                for (int rt = 0; rt < 2; ++rt) {
                    a0[rt] = *reinterpret_cast<const bf16x8*>(
                        h0n_ + (rt * 16 + lr) * 264 + ks * 32 + quad * 8);
                    a1[rt] = *reinterpret_cast<const bf16x8*>(
                        h1s + (rt * 16 + lr) * 264 + ks * 32 + quad * 8);
                }
#pragma unroll
                for (int g2 = 0; g2 < 2; ++g2) {
                    const short* bq0 = g2 ? bq01 : bq00;
                    const short* bq1 = g2 ? bq11 : bq10;
                    const short* bxp = g2 ? bx1 : bx0;
                    const short* bhp = g2 ? bh1 : bh0;
#pragma unroll
                    for (int t = 0; t < 4; ++t) {
                        bf16x8 b = *reinterpret_cast<const bf16x8*>(bq0 + t * 512);
#pragma unroll
                        for (int rt = 0; rt < 2; ++rt)
                            arz[g2][t][rt] = __builtin_amdgcn_mfma_f32_16x16x32_bf16(
                                a0[rt], b, arz[g2][t][rt], 0, 0, 0);
                    }
#pragma unroll
                    for (int nt = 0; nt < 2; ++nt) {
                        bf16x8 b = *reinterpret_cast<const bf16x8*>(bxp + nt * 512);
#pragma unroll
                        for (int rt = 0; rt < 2; ++rt)
                            axn[g2][nt][rt] = __builtin_amdgcn_mfma_f32_16x16x32_bf16(
                                a0[rt], b, axn[g2][nt][rt], 0, 0, 0);
                    }
#pragma unroll
                    for (int t = 0; t < 4; ++t) {
                        bf16x8 b = *reinterpret_cast<const bf16x8*>(bq1 + t * 512);
#pragma unroll
                        for (int rt = 0; rt < 2; ++rt)
                            arz[g2][t][rt] = __builtin_amdgcn_mfma_f32_16x16x32_bf16(
                                a1[rt], b, arz[g2][t][rt], 0, 0, 0);
                    }
#pragma unroll
                    for (int nt = 0; nt < 2; ++nt) {
                        bf16x8 b = *reinterpret_cast<const bf16x8*>(bhp + nt * 512);
#pragma unroll
                        for (int rt = 0; rt < 2; ++rt)
                            ahn[g2][nt][rt] = __builtin_amdgcn_mfma_f32_16x16x32_bf16(
                                a1[rt], b, ahn[g2][nt][rt], 0, 0, 0);
                    }
                }
                bq00 += 4 * 512; bq01 += 4 * 512;
                bq10 += 4 * 512; bq11 += 4 * 512;
                bx0 += 2 * 512;  bx1 += 2 * 512;
                bh0 += 2 * 512;  bh1 += 2 * 512;
            }
            __syncthreads();  // B2: all h1 reads complete
#pragma unroll
            for (int g2 = 0; g2 < 2; ++g2)
#pragma unroll
                for (int nt = 0; nt < 2; ++nt) {
                    const int col = 32 * (2 * w + g2) + nt * 16 + lr;
#pragma unroll
                    for (int rt = 0; rt < 2; ++rt)
#pragma unroll
                        for (int rr = 0; rr < 4; ++rr) {
                            int row = rt * 16 + quad * 4 + rr;
                            float rg = fast_sigmoid(arz[g2][nt][rt][rr]);
                            float zg = fast_sigmoid(arz[g2][2 + nt][rt][rr]);
                            float ng = fast_tanh(axn[g2][nt][rt][rr] +
                                                 rg * ahn[g2][nt][rt][rr]);
                            float hold = bf2f(h1s[row * 264 + col]);
                            h1s[row * 264 + col] =
                                f2bf((1.f - zg) * ng + zg * hold);
                        }
                }
        }
        __syncthreads();  // B3: h1' visible

        // ---------------- delta = h1' @ ow.T + ob ; cumsum -> out
        {
            int brow = tid >> 3, p = tid & 7;   // 32 rows x 8 partials
            float d0 = 0.f, d1 = 0.f;
#pragma unroll
            for (int j = 0; j < 4; ++j) {
                int cb = ((p + brow) & 7) * 8 + j * 64;
                bf16x8 hv8 = *reinterpret_cast<const bf16x8*>(h1s + brow * 264 + cb);
#pragma unroll
                for (int i = 0; i < 8; ++i) {
                    float hv = bf2f(hv8[i]);
                    d0 += hv * owl[cb + i];
                    d1 += hv * owl[256 + cb + i];
                }
            }
            d0 += __shfl_xor(d0, 1); d0 += __shfl_xor(d0, 2); d0 += __shfl_xor(d0, 4);
            d1 += __shfl_xor(d1, 1); d1 += __shfl_xor(d1, 2); d1 += __shfl_xor(d1, 4);
            d0 += ob0v;
            d1 += ob1v;
            if (p == 0) {
                cum0 += d0;
                cum1 += d1;
                size_t o = (((size_t)(b0 + brow) * 3 + m) * (size_t)T + st) * 2;
                out[o] = cum0;
                out[o + 1] = cum1;
                posD[brow * 2] = d0;
                posD[brow * 2 + 1] = d1;
            }
        }
        __syncthreads();  // B4: posD ready
    }
}

extern "C" void kernel_launch(void* const* d_in, const int* in_sizes, int n_in,
                              void* d_out, int out_size, void* d_ws, size_t ws_size,
                              hipStream_t stream) {
    const float* context = (const float*)d_in[0];
    const float* mp_w1 = (const float*)d_in[1];
    const float* mp_b1 = (const float*)d_in[2];
    const float* mp_w2 = (const float*)d_in[3];
    const float* mp_b2 = (const float*)d_in[4];
    const float* w_ih0 = (const float*)d_in[5];
    const float* w_hh0 = (const float*)d_in[6];
    const float* b_ih0 = (const float*)d_in[7];
    const float* b_hh0 = (const float*)d_in[8];
    const float* w_ih1 = (const float*)d_in[9];
    const float* w_hh1 = (const float*)d_in[10];
    const float* b_ih1 = (const float*)d_in[11];
    const float* b_hh1 = (const float*)d_in[12];
    const float* out_w = (const float*)d_in[13];
    const float* out_b = (const float*)d_in[14];
    const int* pT = (const int*)d_in[15];
    float* out = (float*)d_out;
    short* ws = (short*)d_ws;

    const int B = in_sizes[0] / 256;                      // 4096
    const int tilesPerMode = B / 32;                      // 128
    const int nwork = 3 * tilesPerMode;                   // 384
    const long probs_off = (long)out_size - (long)B * 3;

    prep_kernel<<<4608, 64, 0, stream>>>(w_ih0, w_hh0, w_ih1, w_hh1, ws);
    modeprobs_kernel<<<B / 64, 256, 0, stream>>>(context, mp_w1, mp_b1, mp_w2,
                                                 mp_b2, out, probs_off);
    const int grid = 8 * ((nwork + 7) / 8);               // 384
    decoder_kernel<<<grid, 256, 0, stream>>>(
        context, w_ih0, b_ih0, b_hh0, b_ih1, b_hh1, out_w, out_b, ws, out, pT,
        tilesPerMode, nwork);
}

// Round 3
// 1141.812 us; speedup vs baseline: 1.1670x; 1.1670x over previous
//
#include <hip/hip_runtime.h>

// ---------------------------------------------------------------------------
// TrajectoryDecoder: B=4096, F=256, H=256, M=3, T=30 (T read from device)
// out = [trajectories (B,M,T,2) fp32][mode_probs (B,M) fp32]
// R17: R14 structure (64-row x 8-wave blocks, 192 active CUs, 16x16x32,
// 4 barriers/step) with the K-loops split into rz-pass + n-pass per layer.
// Splitting halves live accumulators (128 -> 64 AGPR), freeing ~64 VGPRs
// (R14 was at 252/256 combined) which are spent on a manual 2-deep register
// double-buffer of the 12 B-tiles: iteration ks+1's global loads are issued
// before iteration ks's MFMAs, hiding the ~300-575cy L2 latency that R15's
// boundary-count experiment identified as the dominant stall (~58% stall,
// 42% MFMA-busy on active CUs). r,z persist in 64 VGPRs between passes.
// Same math order as R14 (absmax unchanged). Prep/modeprobs unchanged.
// ---------------------------------------------------------------------------

typedef __attribute__((ext_vector_type(8))) short bf16x8;
typedef __attribute__((ext_vector_type(4))) float f32x4;

__device__ __forceinline__ short f2bf(float f) {
    unsigned u = __builtin_bit_cast(unsigned, f);
    unsigned r = (u + 0x7fffu + ((u >> 16) & 1u)) >> 16;
    return (short)r;
}
__device__ __forceinline__ float bf2f(short s) {
    unsigned u = ((unsigned)(unsigned short)s) << 16;
    return __builtin_bit_cast(float, u);
}
__device__ __forceinline__ float fast_sigmoid(float x) {
    x = fminf(fmaxf(x, -30.f), 30.f);
    float e = __builtin_amdgcn_exp2f(x * -1.442695041f);
    return __builtin_amdgcn_rcpf(1.f + e);
}
__device__ __forceinline__ float fast_tanh(float x) {
    x = fminf(fmaxf(x, -15.f), 15.f);
    float e = __builtin_amdgcn_exp2f(x * -2.885390082f);
    return (1.f - e) * __builtin_amdgcn_rcpf(1.f + e);
}

// ---------------------------------------------------------------------------
// Weight prep: fp32 -> bf16, B-fragment consumption order (R14 layout).
// Regions (1KB blocks):
//   P0  [0,1152):    w_hh0 per (m,w8): 48 = [rz: ks*4+t (32)][n: 32+ks*2+nt]
//   P1  [1152,3456): per (m,w8): 96 = [rz: half*32+ks*4+t (64)]
//                                     [xn: 64+ks*2+nt][hn: 80+ks*2+nt]
//   PC  [3456,4608): w_ih0[:,2:258] per (m,w8): 48 = [ks*6+t6]
// ---------------------------------------------------------------------------
__global__ void prep_kernel(const float* __restrict__ w_ih0,
                            const float* __restrict__ w_hh0,
                            const float* __restrict__ w_ih1,
                            const float* __restrict__ w_hh1,
                            short* __restrict__ ws) {
    int bid = blockIdx.x;
    int L = threadIdx.x;
    const float* src;
    int srcRowLen, colBase, m, w, ks, t;
    if (bid < 1152) {
        int idx = bid, mw = idx / 48, blk = idx % 48;
        m = mw / 8; w = mw % 8;
        if (blk < 32) { ks = blk >> 2; t = blk & 3; }
        else { int q = blk - 32; ks = q >> 1; t = 4 + (q & 1); }
        src = w_hh0 + (size_t)m * 768 * 256; srcRowLen = 256; colBase = 0;
    } else if (bid < 3456) {
        int idx = bid - 1152, mw = idx / 96, blk = idx % 96;
        m = mw / 8; w = mw % 8;
        int half;
        if (blk < 64) { half = blk >> 5; ks = (blk >> 2) & 7; t = blk & 3; }
        else { int q = blk - 64; half = q >> 4; ks = (q >> 1) & 7; t = 4 + (q & 1); }
        src = (half ? w_hh1 : w_ih1) + (size_t)m * 768 * 256;
        srcRowLen = 256; colBase = 0;
    } else {
        int idx = bid - 3456, mw = idx / 48, blk = idx % 48;
        m = mw / 8; w = mw % 8; ks = blk / 6; t = blk % 6;
        src = w_ih0 + (size_t)m * 768 * 258; srcRowLen = 258; colBase = 2;
    }
    int row = (t >> 1) * 256 + 32 * w + (t & 1) * 16 + (L & 15);
    int col0 = colBase + ks * 32 + (L >> 4) * 8;
    short* dst = ws + (size_t)bid * 512 + L * 8;
    const float* s = src + (size_t)row * srcRowLen + col0;
#pragma unroll
    for (int j = 0; j < 8; ++j) dst[j] = f2bf(s[j]);
}

// ---------------------------------------------------------------------------
// Mode-probability MLP
// ---------------------------------------------------------------------------
__global__ __launch_bounds__(256) void modeprobs_kernel(
    const float* __restrict__ ctx, const float* __restrict__ w1,
    const float* __restrict__ b1, const float* __restrict__ w2,
    const float* __restrict__ b2, float* __restrict__ out,
    long probs_off) {
    __shared__ float w1s[64 * 256];
    int tid = threadIdx.x;
    int j = tid & 63;
    int rsub = tid >> 6;
#pragma unroll
    for (int i = 0; i < 64; ++i) w1s[tid + i * 256] = w1[tid + i * 256];
    float b1v = b1[j];
    float w2v0 = w2[j], w2v1 = w2[64 + j], w2v2 = w2[128 + j];
    float b20 = b2[0], b21 = b2[1], b22 = b2[2];
    __syncthreads();
    for (int c = 0; c < 16; ++c) {
        int brow = blockIdx.x * 64 + c * 4 + rsub;
        const float* crow = ctx + (size_t)brow * 256;
        float accv = b1v;
#pragma unroll 8
        for (int k = 0; k < 256; ++k) {
            int kk = (k + j) & 255;
            accv += w1s[j * 256 + kk] * crow[kk];
        }
        float h = fmaxf(accv, 0.f);
        float l0 = h * w2v0, l1 = h * w2v1, l2 = h * w2v2;
#pragma unroll
        for (int s = 1; s < 64; s <<= 1) {
            l0 += __shfl_xor(l0, s);
            l1 += __shfl_xor(l1, s);
            l2 += __shfl_xor(l2, s);
        }
        if (j == 0) {
            l0 += b20; l1 += b21; l2 += b22;
            float mx = fmaxf(l0, fmaxf(l1, l2));
            float e0 = __builtin_amdgcn_exp2f((l0 - mx) * 1.442695041f);
            float e1 = __builtin_amdgcn_exp2f((l1 - mx) * 1.442695041f);
            float e2 = __builtin_amdgcn_exp2f((l2 - mx) * 1.442695041f);
            float inv = 1.f / (e0 + e1 + e2);
            out[probs_off + (size_t)brow * 3 + 0] = e0 * inv;
            out[probs_off + (size_t)brow * 3 + 1] = e1 * inv;
            out[probs_off + (size_t)brow * 3 + 2] = e2 * inv;
        }
    }
}

// ---------------------------------------------------------------------------
// K-loop helpers: rz pass (8 B-tiles/iter, 32 MFMA) and n pass (4 B-tiles,
// 16 MFMA). Loads and MFMAs separated so the driver can prefetch ks+1's
// tiles into the alternate register set before ks's MFMAs issue.
// ---------------------------------------------------------------------------
__device__ __forceinline__ void load_rz(bf16x8 (&bu)[8], const short* pX,
                                        const short* pY, int offX, int offY) {
#pragma unroll
    for (int t = 0; t < 4; ++t) {
        bu[t] = *reinterpret_cast<const bf16x8*>(pX + offX + t * 512);
        bu[4 + t] = *reinterpret_cast<const bf16x8*>(pY + offY + t * 512);
    }
}
__device__ __forceinline__ void mfma_rz(f32x4 (&acc)[4][4], const bf16x8 (&bu)[8],
                                        const short* aP, const short* bP,
                                        int kk, int lr, int quad) {
    bf16x8 a0[4], a1[4];
#pragma unroll
    for (int rt = 0; rt < 4; ++rt) {
        a0[rt] = *reinterpret_cast<const bf16x8*>(
            aP + (rt * 16 + lr) * 264 + kk * 32 + quad * 8);
        a1[rt] = *reinterpret_cast<const bf16x8*>(
            bP + (rt * 16 + lr) * 264 + kk * 32 + quad * 8);
    }
#pragma unroll
    for (int t = 0; t < 4; ++t)
#pragma unroll
        for (int rt = 0; rt < 4; ++rt)
            acc[t][rt] = __builtin_amdgcn_mfma_f32_16x16x32_bf16(
                a0[rt], bu[t], acc[t][rt], 0, 0, 0);
#pragma unroll
    for (int t = 0; t < 4; ++t)
#pragma unroll
        for (int rt = 0; rt < 4; ++rt)
            acc[t][rt] = __builtin_amdgcn_mfma_f32_16x16x32_bf16(
                a1[rt], bu[4 + t], acc[t][rt], 0, 0, 0);
}
__device__ __forceinline__ void load_n(bf16x8 (&bu)[4], const short* pX,
                                       const short* pY, int offX, int offY) {
#pragma unroll
    for (int t = 0; t < 2; ++t) {
        bu[t] = *reinterpret_cast<const bf16x8*>(pX + offX + t * 512);
        bu[2 + t] = *reinterpret_cast<const bf16x8*>(pY + offY + t * 512);
    }
}
__device__ __forceinline__ void mfma_n(f32x4 (&ax)[2][4], f32x4 (&ah)[2][4],
                                       const bf16x8 (&bu)[4], const short* aP,
                                       const short* bP, int kk, int lr, int quad) {
    bf16x8 a0[4], a1[4];
#pragma unroll
    for (int rt = 0; rt < 4; ++rt) {
        a0[rt] = *reinterpret_cast<const bf16x8*>(
            aP + (rt * 16 + lr) * 264 + kk * 32 + quad * 8);
        a1[rt] = *reinterpret_cast<const bf16x8*>(
            bP + (rt * 16 + lr) * 264 + kk * 32 + quad * 8);
    }
#pragma unroll
    for (int nt = 0; nt < 2; ++nt)
#pragma unroll
        for (int rt = 0; rt < 4; ++rt)
            ax[nt][rt] = __builtin_amdgcn_mfma_f32_16x16x32_bf16(
                a0[rt], bu[nt], ax[nt][rt], 0, 0, 0);
#pragma unroll
    for (int nt = 0; nt < 2; ++nt)
#pragma unroll
        for (int rt = 0; rt < 4; ++rt)
            ah[nt][rt] = __builtin_amdgcn_mfma_f32_16x16x32_bf16(
                a1[rt], bu[2 + nt], ah[nt][rt], 0, 0, 0);
}

// ---------------------------------------------------------------------------
// Persistent GRU decoder. Block = 64 batch rows x 1 mode; 512 threads
// (8 waves, wave w owns cols {32w..32w+32} per gate). h0 double-buffered.
// ---------------------------------------------------------------------------
__global__ __launch_bounds__(512, 2) void decoder_kernel(
    const float* __restrict__ context,
    const float* __restrict__ w_ih0_f,   // (3,768,258): pos-weight cols 0..1
    const float* __restrict__ b_ih0, const float* __restrict__ b_hh0,
    const float* __restrict__ b_ih1, const float* __restrict__ b_hh1,
    const float* __restrict__ out_w, const float* __restrict__ out_b,
    const short* __restrict__ ws, float* __restrict__ out,
    const int* __restrict__ pT, int ntiles) {
    __shared__ short ctxS[64 * 264];   // read-only after init
    __shared__ short h0a[64 * 264], h0b[64 * 264];  // double-buffered h0
    __shared__ short h1s[64 * 264];
    __shared__ float posD[128];
    __shared__ float owl[512];
    __shared__ float cwp0[768], cwp1[768];  // w_ih0[:,0], w_ih0[:,1]
    __shared__ float cbA[512];              // L0 rz: b_ih0+b_hh0
    __shared__ float cbXn[256];             // L0 n:  b_ih0
    __shared__ float cbh0n[256];            // L0 n:  b_hh0
    __shared__ float cb1A[512];             // L1 rz: b_ih1+b_hh1
    __shared__ float cb1X[256];             // L1 n:  b_ih1
    __shared__ float cb1H[256];             // L1 n:  b_hh1

    const int bid = blockIdx.x;
    const int xcd = bid & 7, slot = bid >> 3;
    int mode, xl, nx;
    if (xcd < 3)      { mode = 0; xl = xcd;     nx = 3; }
    else if (xcd < 6) { mode = 1; xl = xcd - 3; nx = 3; }
    else              { mode = 2; xl = xcd - 6; nx = 2; }
    const int g = slot * nx + xl;
    if (g >= ntiles) return;
    const int m = mode;
    const int b0 = g * 64;

    const int T = *pT;
    const int tid = threadIdx.x;
    const int lane = tid & 63, w = tid >> 6;
    const int lr = lane & 15, quad = lane >> 4;

    if (tid < 128) posD[tid] = 0.f;
    owl[tid] = out_w[m * 512 + tid];
    if (tid < 512) {
        cbA[tid] = b_ih0[m * 768 + tid] + b_hh0[m * 768 + tid];
        cb1A[tid] = b_ih1[m * 768 + tid] + b_hh1[m * 768 + tid];
    }
    if (tid < 256) {
        cbXn[tid] = b_ih0[m * 768 + 512 + tid];
        cbh0n[tid] = b_hh0[m * 768 + 512 + tid];
        cb1X[tid] = b_ih1[m * 768 + 512 + tid];
        cb1H[tid] = b_hh1[m * 768 + 512 + tid];
    }
    for (int cc = tid; cc < 768; cc += 512) {
        cwp0[cc] = w_ih0_f[((size_t)m * 768 + cc) * 258 + 0];
        cwp1[cc] = w_ih0_f[((size_t)m * 768 + cc) * 258 + 1];
    }
#pragma unroll
    for (int i = 0; i < 32; ++i) {
        int idx = tid + i * 512;
        int r = idx >> 8, k = idx & 255;
        short v = f2bf(context[(size_t)(b0 + r) * 256 + k]);
        ctxS[r * 264 + k] = v;
        h0a[r * 264 + k] = v;
        h1s[r * 264 + k] = v;
    }
    const float ob0v = out_b[m * 2 + 0], ob1v = out_b[m * 2 + 1];

    const short* p0w = ws + ((size_t)(m * 8 + w) * 48) * 512 + lane * 8;
    const short* p1w = ws + (size_t)1152 * 512 + ((size_t)(m * 8 + w) * 96) * 512 + lane * 8;
    const short* pcw = ws + (size_t)3456 * 512 + ((size_t)(m * 8 + w) * 48) * 512 + lane * 8;
    const short* p0n = p0w + 32 * 512;   // w_hh0 n tiles
    const short* p1x = p1w + 64 * 512;   // w_ih1 xn tiles
    const short* p1h = p1w + 80 * 512;   // w_hh1 hn tiles
    const short* p1q = p1w + 32 * 512;   // w_hh1 rz tiles

    const int cA = 32 * w + lr;        // n-tile 0 col (and rz tile base)
    const int cB = 32 * w + 16 + lr;   // n-tile 1 col

    __syncthreads();

    float cum0 = 0.f, cum1 = 0.f;

    for (int st = 0; st < T; ++st) {
        const short* h0c = (st & 1) ? h0b : h0a;   // current h0
        short* h0n_ = (st & 1) ? h0a : h0b;        // next h0 (no WAR hazard)

        // ======== layer 0 ========
        float rv[2][4][4], zv[2][4][4];
        {
            // ---- pass A: rz (acc 64, B-dbuf 8 tiles x2) ----
            f32x4 arz[4][4];
#pragma unroll
            for (int rt = 0; rt < 4; ++rt)
#pragma unroll
                for (int r = 0; r < 4; ++r) {
                    int row = rt * 16 + quad * 4 + r;
                    float px = posD[row * 2], py = posD[row * 2 + 1];
#pragma unroll
                    for (int t = 0; t < 4; ++t) {
                        int c = (t >> 1) * 256 + ((t & 1) ? cB : cA);
                        arz[t][rt][r] = cbA[c] + px * cwp0[c] + py * cwp1[c];
                    }
                }
            {
                bf16x8 bu0[8], bu1[8];
                load_rz(bu0, pcw, p0w, 0, 0);
#pragma unroll 1
                for (int ks2 = 0; ks2 < 4; ++ks2) {
                    int k0 = 2 * ks2, k1 = k0 + 1, k2 = k0 + 2;
                    load_rz(bu1, pcw, p0w, k1 * 6 * 512, k1 * 4 * 512);
                    mfma_rz(arz, bu0, ctxS, h0c, k0, lr, quad);
                    if (ks2 < 3)
                        load_rz(bu0, pcw, p0w, k2 * 6 * 512, k2 * 4 * 512);
                    mfma_rz(arz, bu1, ctxS, h0c, k1, lr, quad);
                }
            }
#pragma unroll
            for (int nt = 0; nt < 2; ++nt)
#pragma unroll
                for (int rt = 0; rt < 4; ++rt)
#pragma unroll
                    for (int r = 0; r < 4; ++r) {
                        rv[nt][rt][r] = fast_sigmoid(arz[nt][rt][r]);
                        zv[nt][rt][r] = fast_sigmoid(arz[2 + nt][rt][r]);
                    }
        }
        {
            // ---- pass B: n (acc 64, B-dbuf 4 tiles x2), combine, write ----
            f32x4 axn[2][4], ahn[2][4];
#pragma unroll
            for (int rt = 0; rt < 4; ++rt)
#pragma unroll
                for (int r = 0; r < 4; ++r) {
                    int row = rt * 16 + quad * 4 + r;
                    float px = posD[row * 2], py = posD[row * 2 + 1];
#pragma unroll
                    for (int nt = 0; nt < 2; ++nt) {
                        int cn = nt ? cB : cA;
                        axn[nt][rt][r] = cbXn[cn] + px * cwp0[512 + cn] +
                                         py * cwp1[512 + cn];
                        ahn[nt][rt][r] = cbh0n[cn];
                    }
                }
            {
                bf16x8 bu0[4], bu1[4];
                load_n(bu0, pcw, p0n, 4 * 512, 0);
#pragma unroll 1
                for (int ks2 = 0; ks2 < 4; ++ks2) {
                    int k0 = 2 * ks2, k1 = k0 + 1, k2 = k0 + 2;
                    load_n(bu1, pcw, p0n, (k1 * 6 + 4) * 512, k1 * 2 * 512);
                    mfma_n(axn, ahn, bu0, ctxS, h0c, k0, lr, quad);
                    if (ks2 < 3)
                        load_n(bu0, pcw, p0n, (k2 * 6 + 4) * 512, k2 * 2 * 512);
                    mfma_n(axn, ahn, bu1, ctxS, h0c, k1, lr, quad);
                }
            }
            // no barrier: epilogue writes h0n_ (other buffer), no WAR hazard
#pragma unroll
            for (int nt = 0; nt < 2; ++nt) {
                int col = nt ? cB : cA;
#pragma unroll
                for (int rt = 0; rt < 4; ++rt)
#pragma unroll
                    for (int r = 0; r < 4; ++r) {
                        int row = rt * 16 + quad * 4 + r;
                        float nn = fast_tanh(axn[nt][rt][r] +
                                             rv[nt][rt][r] * ahn[nt][rt][r]);
                        float hold = bf2f(h0c[row * 264 + col]);
                        h0n_[row * 264 + col] =
                            f2bf((1.f - zv[nt][rt][r]) * nn +
                                 zv[nt][rt][r] * hold);
                    }
            }
        }
        __syncthreads();  // B1: h0' visible

        // ======== layer 1 ========
        {
            // ---- pass A: rz ----
            f32x4 arz[4][4];
#pragma unroll
            for (int rt = 0; rt < 4; ++rt)
#pragma unroll
                for (int r = 0; r < 4; ++r)
#pragma unroll
                    for (int t = 0; t < 4; ++t) {
                        int c = (t >> 1) * 256 + ((t & 1) ? cB : cA);
                        arz[t][rt][r] = cb1A[c];
                    }
            {
                bf16x8 bu0[8], bu1[8];
                load_rz(bu0, p1w, p1q, 0, 0);
#pragma unroll 1
                for (int ks2 = 0; ks2 < 4; ++ks2) {
                    int k0 = 2 * ks2, k1 = k0 + 1, k2 = k0 + 2;
                    load_rz(bu1, p1w, p1q, k1 * 4 * 512, k1 * 4 * 512);
                    mfma_rz(arz, bu0, h0n_, h1s, k0, lr, quad);
                    if (ks2 < 3)
                        load_rz(bu0, p1w, p1q, k2 * 4 * 512, k2 * 4 * 512);
                    mfma_rz(arz, bu1, h0n_, h1s, k1, lr, quad);
                }
            }
#pragma unroll
            for (int nt = 0; nt < 2; ++nt)
#pragma unroll
                for (int rt = 0; rt < 4; ++rt)
#pragma unroll
                    for (int r = 0; r < 4; ++r) {
                        rv[nt][rt][r] = fast_sigmoid(arz[nt][rt][r]);
                        zv[nt][rt][r] = fast_sigmoid(arz[2 + nt][rt][r]);
                    }
        }
        {
            // ---- pass B: n, combine, write h1 ----
            f32x4 axn[2][4], ahn[2][4];
#pragma unroll
            for (int rt = 0; rt < 4; ++rt)
#pragma unroll
                for (int r = 0; r < 4; ++r)
#pragma unroll
                    for (int nt = 0; nt < 2; ++nt) {
                        int cn = nt ? cB : cA;
                        axn[nt][rt][r] = cb1X[cn];
                        ahn[nt][rt][r] = cb1H[cn];
                    }
            {
                bf16x8 bu0[4], bu1[4];
                load_n(bu0, p1x, p1h, 0, 0);
#pragma unroll 1
                for (int ks2 = 0; ks2 < 4; ++ks2) {
                    int k0 = 2 * ks2, k1 = k0 + 1, k2 = k0 + 2;
                    load_n(bu1, p1x, p1h, k1 * 2 * 512, k1 * 2 * 512);
                    mfma_n(axn, ahn, bu0, h0n_, h1s, k0, lr, quad);
                    if (ks2 < 3)
                        load_n(bu0, p1x, p1h, k2 * 2 * 512, k2 * 2 * 512);
                    mfma_n(axn, ahn, bu1, h0n_, h1s, k1, lr, quad);
                }
            }
            __syncthreads();  // B2: all h1 reads complete
#pragma unroll
            for (int nt = 0; nt < 2; ++nt) {
                int col = nt ? cB : cA;
#pragma unroll
                for (int rt = 0; rt < 4; ++rt)
#pragma unroll
                    for (int r = 0; r < 4; ++r) {
                        int row = rt * 16 + quad * 4 + r;
                        float nn = fast_tanh(axn[nt][rt][r] +
                                             rv[nt][rt][r] * ahn[nt][rt][r]);
                        float hold = bf2f(h1s[row * 264 + col]);
                        h1s[row * 264 + col] =
                            f2bf((1.f - zv[nt][rt][r]) * nn +
                                 zv[nt][rt][r] * hold);
                    }
            }
        }
        __syncthreads();  // B3: h1' visible

        // ---------------- delta = h1' @ ow.T + ob ; cumsum -> out
        {
            int brow = tid >> 3, p = tid & 7;
            float d0 = 0.f, d1 = 0.f;
#pragma unroll
            for (int j = 0; j < 4; ++j) {
                int cb = ((p + brow) & 7) * 8 + j * 64;
                bf16x8 hv8 = *reinterpret_cast<const bf16x8*>(h1s + brow * 264 + cb);
#pragma unroll
                for (int i = 0; i < 8; ++i) {
                    float hv = bf2f(hv8[i]);
                    d0 += hv * owl[cb + i];
                    d1 += hv * owl[256 + cb + i];
                }
            }
            d0 += __shfl_xor(d0, 1); d0 += __shfl_xor(d0, 2); d0 += __shfl_xor(d0, 4);
            d1 += __shfl_xor(d1, 1); d1 += __shfl_xor(d1, 2); d1 += __shfl_xor(d1, 4);
            d0 += ob0v;
            d1 += ob1v;
            if (p == 0) {
                cum0 += d0;
                cum1 += d1;
                size_t o = (((size_t)(b0 + brow) * 3 + m) * (size_t)T + st) * 2;
                out[o] = cum0;
                out[o + 1] = cum1;
                posD[brow * 2] = d0;
                posD[brow * 2 + 1] = d1;
            }
        }
        __syncthreads();  // B4: posD ready
    }
}

extern "C" void kernel_launch(void* const* d_in, const int* in_sizes, int n_in,
                              void* d_out, int out_size, void* d_ws, size_t ws_size,
                              hipStream_t stream) {
    const float* context = (const float*)d_in[0];
    const float* mp_w1 = (const float*)d_in[1];
    const float* mp_b1 = (const float*)d_in[2];
    const float* mp_w2 = (const float*)d_in[3];
    const float* mp_b2 = (const float*)d_in[4];
    const float* w_ih0 = (const float*)d_in[5];
    const float* w_hh0 = (const float*)d_in[6];
    const float* b_ih0 = (const float*)d_in[7];
    const float* b_hh0 = (const float*)d_in[8];
    const float* w_ih1 = (const float*)d_in[9];
    const float* w_hh1 = (const float*)d_in[10];
    const float* b_ih1 = (const float*)d_in[11];
    const float* b_hh1 = (const float*)d_in[12];
    const float* out_w = (const float*)d_in[13];
    const float* out_b = (const float*)d_in[14];
    const int* pT = (const int*)d_in[15];
    float* out = (float*)d_out;
    short* ws = (short*)d_ws;

    const int B = in_sizes[0] / 256;                      // 4096
    const int ntiles = B / 64;                            // 64
    const long probs_off = (long)out_size - (long)B * 3;

    prep_kernel<<<4608, 64, 0, stream>>>(w_ih0, w_hh0, w_ih1, w_hh1, ws);
    modeprobs_kernel<<<B / 64, 256, 0, stream>>>(context, mp_w1, mp_b1, mp_w2,
                                                 mp_b2, out, probs_off);
    const int nslots = (ntiles + 1) / 2;
    decoder_kernel<<<8 * nslots, 512, 0, stream>>>(
        context, w_ih0, b_ih0, b_hh0, b_ih1, b_hh1, out_w, out_b, ws, out, pT,
        ntiles);
}

// Round 4
// 988.138 us; speedup vs baseline: 1.3485x; 1.1555x over previous
//
#include <hip/hip_runtime.h>

// ---------------------------------------------------------------------------
// TrajectoryDecoder: B=4096, F=256, H=256, M=3, T=30 (T read from device)
// out = [trajectories (B,M,T,2) fp32][mode_probs (B,M) fp32]
// R18: R14 structure (64-row x 8-wave blocks, 16x16x32, merged rz+n) with the
// K-loop B-tiles staged through per-wave LDS via global_load_lds (ZERO VGPR
// cost -- R17 proved register prefetch spills at the 252/256 budget). Each
// K-iter = 4 phases: vmcnt(3) -> ds_read 3 B-tiles -> lgkmcnt(0) -> DMA-issue
// phase p+2 -> 12 MFMA. Counted vmcnt (never 0 in-loop); pipeline continuous
// across layers AND steps (L1 tiles issued during L0 ks=7, next step's ctx
// tiles during L1 ks=7). All step-loop barriers are raw lgkmcnt(0)+s_barrier
// so in-flight DMAs ride through (h-state hazards are DS-domain only).
// LDS 162,304B: h0 dbuf dropped (5 barriers/step), cwp + n-biases as bf16,
// stg[8][2][3][512]. MFMA accumulation order bitwise-identical to R14.
// ---------------------------------------------------------------------------

typedef __attribute__((ext_vector_type(8))) short bf16x8;
typedef __attribute__((ext_vector_type(4))) float f32x4;

__device__ __forceinline__ short f2bf(float f) {
    unsigned u = __builtin_bit_cast(unsigned, f);
    unsigned r = (u + 0x7fffu + ((u >> 16) & 1u)) >> 16;
    return (short)r;
}
__device__ __forceinline__ float bf2f(short s) {
    unsigned u = ((unsigned)(unsigned short)s) << 16;
    return __builtin_bit_cast(float, u);
}
__device__ __forceinline__ float fast_sigmoid(float x) {
    x = fminf(fmaxf(x, -30.f), 30.f);
    float e = __builtin_amdgcn_exp2f(x * -1.442695041f);
    return __builtin_amdgcn_rcpf(1.f + e);
}
__device__ __forceinline__ float fast_tanh(float x) {
    x = fminf(fmaxf(x, -15.f), 15.f);
    float e = __builtin_amdgcn_exp2f(x * -2.885390082f);
    return (1.f - e) * __builtin_amdgcn_rcpf(1.f + e);
}

// ---------------------------------------------------------------------------
// Weight prep: fp32 -> bf16, B-fragment consumption order (R14 layout).
// Regions (1KB blocks):
//   P0  [0,1152):    w_hh0 per (m,w8): 48 = [rz: ks*4+t (32)][n: 32+ks*2+nt]
//   P1  [1152,3456): per (m,w8): 96 = [rz: half*32+ks*4+t (64)]
//                                     [xn: 64+ks*2+nt][hn: 80+ks*2+nt]
//   PC  [3456,4608): w_ih0[:,2:258] per (m,w8): 48 = [ks*6+t6]
// ---------------------------------------------------------------------------
__global__ void prep_kernel(const float* __restrict__ w_ih0,
                            const float* __restrict__ w_hh0,
                            const float* __restrict__ w_ih1,
                            const float* __restrict__ w_hh1,
                            short* __restrict__ ws) {
    int bid = blockIdx.x;
    int L = threadIdx.x;
    const float* src;
    int srcRowLen, colBase, m, w, ks, t;
    if (bid < 1152) {
        int idx = bid, mw = idx / 48, blk = idx % 48;
        m = mw / 8; w = mw % 8;
        if (blk < 32) { ks = blk >> 2; t = blk & 3; }
        else { int q = blk - 32; ks = q >> 1; t = 4 + (q & 1); }
        src = w_hh0 + (size_t)m * 768 * 256; srcRowLen = 256; colBase = 0;
    } else if (bid < 3456) {
        int idx = bid - 1152, mw = idx / 96, blk = idx % 96;
        m = mw / 8; w = mw % 8;
        int half;
        if (blk < 64) { half = blk >> 5; ks = (blk >> 2) & 7; t = blk & 3; }
        else { int q = blk - 64; half = q >> 4; ks = (q >> 1) & 7; t = 4 + (q & 1); }
        src = (half ? w_hh1 : w_ih1) + (size_t)m * 768 * 256;
        srcRowLen = 256; colBase = 0;
    } else {
        int idx = bid - 3456, mw = idx / 48, blk = idx % 48;
        m = mw / 8; w = mw % 8; ks = blk / 6; t = blk % 6;
        src = w_ih0 + (size_t)m * 768 * 258; srcRowLen = 258; colBase = 2;
    }
    int row = (t >> 1) * 256 + 32 * w + (t & 1) * 16 + (L & 15);
    int col0 = colBase + ks * 32 + (L >> 4) * 8;
    short* dst = ws + (size_t)bid * 512 + L * 8;
    const float* s = src + (size_t)row * srcRowLen + col0;
#pragma unroll
    for (int j = 0; j < 8; ++j) dst[j] = f2bf(s[j]);
}

// ---------------------------------------------------------------------------
// Mode-probability MLP
// ---------------------------------------------------------------------------
__global__ __launch_bounds__(256) void modeprobs_kernel(
    const float* __restrict__ ctx, const float* __restrict__ w1,
    const float* __restrict__ b1, const float* __restrict__ w2,
    const float* __restrict__ b2, float* __restrict__ out,
    long probs_off) {
    __shared__ float w1s[64 * 256];
    int tid = threadIdx.x;
    int j = tid & 63;
    int rsub = tid >> 6;
#pragma unroll
    for (int i = 0; i < 64; ++i) w1s[tid + i * 256] = w1[tid + i * 256];
    float b1v = b1[j];
    float w2v0 = w2[j], w2v1 = w2[64 + j], w2v2 = w2[128 + j];
    float b20 = b2[0], b21 = b2[1], b22 = b2[2];
    __syncthreads();
    for (int c = 0; c < 16; ++c) {
        int brow = blockIdx.x * 64 + c * 4 + rsub;
        const float* crow = ctx + (size_t)brow * 256;
        float accv = b1v;
#pragma unroll 8
        for (int k = 0; k < 256; ++k) {
            int kk = (k + j) & 255;
            accv += w1s[j * 256 + kk] * crow[kk];
        }
        float h = fmaxf(accv, 0.f);
        float l0 = h * w2v0, l1 = h * w2v1, l2 = h * w2v2;
#pragma unroll
        for (int s = 1; s < 64; s <<= 1) {
            l0 += __shfl_xor(l0, s);
            l1 += __shfl_xor(l1, s);
            l2 += __shfl_xor(l2, s);
        }
        if (j == 0) {
            l0 += b20; l1 += b21; l2 += b22;
            float mx = fmaxf(l0, fmaxf(l1, l2));
            float e0 = __builtin_amdgcn_exp2f((l0 - mx) * 1.442695041f);
            float e1 = __builtin_amdgcn_exp2f((l1 - mx) * 1.442695041f);
            float e2 = __builtin_amdgcn_exp2f((l2 - mx) * 1.442695041f);
            float inv = 1.f / (e0 + e1 + e2);
            out[probs_off + (size_t)brow * 3 + 0] = e0 * inv;
            out[probs_off + (size_t)brow * 3 + 1] = e1 * inv;
            out[probs_off + (size_t)brow * 3 + 2] = e2 * inv;
        }
    }
}

// ---------------------------------------------------------------------------
// Staging + phase helpers
// ---------------------------------------------------------------------------
__device__ __forceinline__ void gl16(const short* g, short* l) {
    // per-lane global src (g already includes lane*8), wave-uniform LDS dest;
    // HW writes lane L at dest + L*16B -- matches the lane-linear tile layout.
    __builtin_amdgcn_global_load_lds(
        (const __attribute__((address_space(1))) unsigned int*)g,
        (__attribute__((address_space(3))) unsigned int*)l, 16, 0, 0);
}
__device__ __forceinline__ void barrier_lgkm() {
    // raw barrier: drain DS ops only; global_load_lds DMAs ride through.
    asm volatile("s_waitcnt lgkmcnt(0)" ::: "memory");
    __builtin_amdgcn_s_barrier();
}
// One phase: wait tiles, read 3 B-frags, issue phase p+2's 3 tiles, 12 MFMA.
__device__ __forceinline__ void phase3(const short* rbuf,  // stgR + buf*1536
                                       const short* i0, const short* i1,
                                       const short* i2,
                                       short* wbuf,        // stgW + buf*1536
                                       const bf16x8 (&a)[4], f32x4 (&A0)[4],
                                       f32x4 (&A1)[4], f32x4 (&A2)[4]) {
    asm volatile("s_waitcnt vmcnt(3)" ::: "memory");
    bf16x8 b0 = *reinterpret_cast<const bf16x8*>(rbuf);
    bf16x8 b1 = *reinterpret_cast<const bf16x8*>(rbuf + 512);
    bf16x8 b2 = *reinterpret_cast<const bf16x8*>(rbuf + 1024);
    asm volatile("s_waitcnt lgkmcnt(0)" ::: "memory");
    __builtin_amdgcn_sched_barrier(0);
    gl16(i0, wbuf);
    gl16(i1, wbuf + 512);
    gl16(i2, wbuf + 1024);
#pragma unroll
    for (int rt = 0; rt < 4; ++rt)
        A0[rt] = __builtin_amdgcn_mfma_f32_16x16x32_bf16(a[rt], b0, A0[rt], 0, 0, 0);
#pragma unroll
    for (int rt = 0; rt < 4; ++rt)
        A1[rt] = __builtin_amdgcn_mfma_f32_16x16x32_bf16(a[rt], b1, A1[rt], 0, 0, 0);
#pragma unroll
    for (int rt = 0; rt < 4; ++rt)
        A2[rt] = __builtin_amdgcn_mfma_f32_16x16x32_bf16(a[rt], b2, A2[rt], 0, 0, 0);
}

// ---------------------------------------------------------------------------
// Persistent GRU decoder. Block = 64 batch rows x 1 mode; 512 threads
// (8 waves, wave w owns cols {32w..32w+32} per gate). Single h0 buffer,
// 5 raw barriers/step. Per-wave LDS B-staging, 2-phase-ahead counted vmcnt.
// ---------------------------------------------------------------------------
__global__ __launch_bounds__(512, 2) void decoder_kernel(
    const float* __restrict__ context,
    const float* __restrict__ w_ih0_f,   // (3,768,258): pos-weight cols 0..1
    const float* __restrict__ b_ih0, const float* __restrict__ b_hh0,
    const float* __restrict__ b_ih1, const float* __restrict__ b_hh1,
    const float* __restrict__ out_w, const float* __restrict__ out_b,
    const short* __restrict__ ws, float* __restrict__ out,
    const int* __restrict__ pT, int ntiles) {
    __shared__ short ctxS[64 * 264];   // read-only after init
    __shared__ short h0s[64 * 264];    // h0 (in-place update)
    __shared__ short h1s[64 * 264];    // h1 (in-place update)
    __shared__ short stg[8 * 3072];    // per-wave B staging: [8][2 buf][3][512]
    __shared__ float posD[128];
    __shared__ float owl[512];
    __shared__ short cwp0h[768], cwp1h[768];  // w_ih0[:,0],[:,1] as bf16
    __shared__ float cbA[512];                // L0 rz: b_ih0+b_hh0
    __shared__ float cb1A[512];               // L1 rz: b_ih1+b_hh1
    __shared__ short cbXn[256], cbh0n[256];   // L0 n biases (bf16)
    __shared__ short cb1X[256], cb1H[256];    // L1 n biases (bf16)

    const int bid = blockIdx.x;
    const int xcd = bid & 7, slot = bid >> 3;
    int mode, xl, nx;
    if (xcd < 3)      { mode = 0; xl = xcd;     nx = 3; }
    else if (xcd < 6) { mode = 1; xl = xcd - 3; nx = 3; }
    else              { mode = 2; xl = xcd - 6; nx = 2; }
    const int g = slot * nx + xl;
    if (g >= ntiles) return;
    const int m = mode;
    const int b0 = g * 64;

    const int T = *pT;
    const int tid = threadIdx.x;
    const int lane = tid & 63, w = tid >> 6;
    const int lr = lane & 15, quad = lane >> 4;

    if (tid < 128) posD[tid] = 0.f;
    owl[tid] = out_w[m * 512 + tid];
    cbA[tid] = b_ih0[m * 768 + tid] + b_hh0[m * 768 + tid];
    cb1A[tid] = b_ih1[m * 768 + tid] + b_hh1[m * 768 + tid];
    if (tid < 256) {
        cbXn[tid] = f2bf(b_ih0[m * 768 + 512 + tid]);
        cbh0n[tid] = f2bf(b_hh0[m * 768 + 512 + tid]);
        cb1X[tid] = f2bf(b_ih1[m * 768 + 512 + tid]);
        cb1H[tid] = f2bf(b_hh1[m * 768 + 512 + tid]);
    }
    for (int cc = tid; cc < 768; cc += 512) {
        cwp0h[cc] = f2bf(w_ih0_f[((size_t)m * 768 + cc) * 258 + 0]);
        cwp1h[cc] = f2bf(w_ih0_f[((size_t)m * 768 + cc) * 258 + 1]);
    }
#pragma unroll
    for (int i = 0; i < 32; ++i) {
        int idx = tid + i * 512;
        int r = idx >> 8, k = idx & 255;
        short v = f2bf(context[(size_t)(b0 + r) * 256 + k]);
        ctxS[r * 264 + k] = v;
        h0s[r * 264 + k] = v;
        h1s[r * 264 + k] = v;
    }
    const float ob0v = out_b[m * 2 + 0], ob1v = out_b[m * 2 + 1];

    // lane-adjusted global tile bases (R14 ws layout)
    const short* p0w = ws + ((size_t)(m * 8 + w) * 48) * 512 + lane * 8;
    const short* p1w = ws + (size_t)1152 * 512 + ((size_t)(m * 8 + w) * 96) * 512 + lane * 8;
    const short* pcw = ws + (size_t)3456 * 512 + ((size_t)(m * 8 + w) * 48) * 512 + lane * 8;
    const short* p0n = p0w + 32 * 512;   // w_hh0 n tiles
    const short* p1q = p1w + 32 * 512;   // w_hh1 rz tiles
    const short* p1x = p1w + 64 * 512;   // w_ih1 xn tiles
    const short* p1h = p1w + 80 * 512;   // w_hh1 hn tiles

    // per-wave staging pointers
    short* stgW = stg + w * 3072;              // uniform (DMA dest base)
    const short* stgR = stgW + lane * 8;       // per-lane read base

    const int cA = 32 * w + lr;        // n-tile 0 col (and rz tile base)
    const int cB = 32 * w + 16 + lr;   // n-tile 1 col

    __syncthreads();

    // prologue: stage L0(ks=0) P0 (ctx j0..2 -> buf0), P1 (ctx j3..5 -> buf1)
    gl16(pcw, stgW);
    gl16(pcw + 512, stgW + 512);
    gl16(pcw + 2 * 512, stgW + 2 * 512);
    gl16(pcw + 3 * 512, stgW + 1536);
    gl16(pcw + 4 * 512, stgW + 1536 + 512);
    gl16(pcw + 5 * 512, stgW + 1536 + 1024);

    float cum0 = 0.f, cum1 = 0.f;

    for (int st = 0; st < T; ++st) {
        // ======== layer 0 (merged rz+n, 4-phase staged K-loop) ========
        {
            f32x4 arz[4][4], axn[2][4], ahn[2][4];
#pragma unroll
            for (int rt = 0; rt < 4; ++rt)
#pragma unroll
                for (int r = 0; r < 4; ++r) {
                    int row = rt * 16 + quad * 4 + r;
                    float px = posD[row * 2], py = posD[row * 2 + 1];
#pragma unroll
                    for (int t = 0; t < 4; ++t) {
                        int c = (t >> 1) * 256 + ((t & 1) ? cB : cA);
                        arz[t][rt][r] = cbA[c] + px * bf2f(cwp0h[c]) +
                                        py * bf2f(cwp1h[c]);
                    }
#pragma unroll
                    for (int nt = 0; nt < 2; ++nt) {
                        int cn = nt ? cB : cA;
                        axn[nt][rt][r] = bf2f(cbXn[cn]) +
                                         px * bf2f(cwp0h[512 + cn]) +
                                         py * bf2f(cwp1h[512 + cn]);
                        ahn[nt][rt][r] = bf2f(cbh0n[cn]);
                    }
                }
            const short* ih = p0w;
            const short* in_ = p0n;
            const short* ic = pcw + 6 * 512;
#pragma unroll 1
            for (int ks = 0; ks < 8; ++ks) {
                bf16x8 ac[4], ah[4];
#pragma unroll
                for (int rt = 0; rt < 4; ++rt)
                    ac[rt] = *reinterpret_cast<const bf16x8*>(
                        ctxS + (rt * 16 + lr) * 264 + ks * 32 + quad * 8);
                phase3(stgR, ih, ih + 512, ih + 2 * 512, stgW, ac,
                       arz[0], arz[1], arz[2]);
                phase3(stgR + 1536, ih + 3 * 512, in_, in_ + 512, stgW + 1536,
                       ac, arz[3], axn[0], axn[1]);
#pragma unroll
                for (int rt = 0; rt < 4; ++rt)
                    ah[rt] = *reinterpret_cast<const bf16x8*>(
                        h0s + (rt * 16 + lr) * 264 + ks * 32 + quad * 8);
                const short* nA = (ks < 7) ? ic : p1w;
                const short* nB0 = (ks < 7) ? ic + 4 * 512 : p1x;
                const short* nB1 = (ks < 7) ? ic + 5 * 512 : p1x + 512;
                phase3(stgR, nA, nA + 512, nA + 2 * 512, stgW, ah,
                       arz[0], arz[1], arz[2]);
                phase3(stgR + 1536, nA + 3 * 512, nB0, nB1, stgW + 1536, ah,
                       arz[3], ahn[0], ahn[1]);
                ih += 4 * 512;
                in_ += 2 * 512;
                ic += 6 * 512;
            }
            barrier_lgkm();  // B1a: all h0s reads complete
#pragma unroll
            for (int nt = 0; nt < 2; ++nt) {
                int col = nt ? cB : cA;
#pragma unroll
                for (int rt = 0; rt < 4; ++rt)
#pragma unroll
                    for (int r = 0; r < 4; ++r) {
                        int row = rt * 16 + quad * 4 + r;
                        float rr = fast_sigmoid(arz[nt][rt][r]);
                        float zz = fast_sigmoid(arz[2 + nt][rt][r]);
                        float nn =
                            fast_tanh(axn[nt][rt][r] + rr * ahn[nt][rt][r]);
                        float hold = bf2f(h0s[row * 264 + col]);
                        h0s[row * 264 + col] = f2bf((1.f - zz) * nn + zz * hold);
                    }
            }
        }
        barrier_lgkm();  // B1b: h0' visible

        // ======== layer 1 (merged rz+n, 4-phase staged K-loop) ========
        {
            f32x4 arz[4][4], axn[2][4], ahn[2][4];
#pragma unroll
            for (int rt = 0; rt < 4; ++rt)
#pragma unroll
                for (int r = 0; r < 4; ++r) {
#pragma unroll
                    for (int t = 0; t < 4; ++t) {
                        int c = (t >> 1) * 256 + ((t & 1) ? cB : cA);
                        arz[t][rt][r] = cb1A[c];
                    }
#pragma unroll
                    for (int nt = 0; nt < 2; ++nt) {
                        int cn = nt ? cB : cA;
                        axn[nt][rt][r] = bf2f(cb1X[cn]);
                        ahn[nt][rt][r] = bf2f(cb1H[cn]);
                    }
                }
            const short* iq1 = p1q;
            const short* iy = p1h;
            const short* iq0 = p1w + 4 * 512;
            const short* ix = p1x + 2 * 512;
#pragma unroll 1
            for (int ks = 0; ks < 8; ++ks) {
                bf16x8 a0[4], a1[4];
#pragma unroll
                for (int rt = 0; rt < 4; ++rt)
                    a0[rt] = *reinterpret_cast<const bf16x8*>(
                        h0s + (rt * 16 + lr) * 264 + ks * 32 + quad * 8);
                phase3(stgR, iq1, iq1 + 512, iq1 + 2 * 512, stgW, a0,
                       arz[0], arz[1], arz[2]);
                phase3(stgR + 1536, iq1 + 3 * 512, iy, iy + 512, stgW + 1536,
                       a0, arz[3], axn[0], axn[1]);
#pragma unroll
                for (int rt = 0; rt < 4; ++rt)
                    a1[rt] = *reinterpret_cast<const bf16x8*>(
                        h1s + (rt * 16 + lr) * 264 + ks * 32 + quad * 8);
                const short* mA = (ks < 7) ? iq0 : pcw;
                const short* mB0 = (ks < 7) ? ix : pcw + 4 * 512;
                const short* mB1 = (ks < 7) ? ix + 512 : pcw + 5 * 512;
                phase3(stgR, mA, mA + 512, mA + 2 * 512, stgW, a1,
                       arz[0], arz[1], arz[2]);
                phase3(stgR + 1536, mA + 3 * 512, mB0, mB1, stgW + 1536, a1,
                       arz[3], ahn[0], ahn[1]);
                iq1 += 4 * 512;
                iy += 2 * 512;
                iq0 += 4 * 512;
                ix += 2 * 512;
            }
            barrier_lgkm();  // B2: all h1s reads complete
#pragma unroll
            for (int nt = 0; nt < 2; ++nt) {
                int col = nt ? cB : cA;
#pragma unroll
                for (int rt = 0; rt < 4; ++rt)
#pragma unroll
                    for (int r = 0; r < 4; ++r) {
                        int row = rt * 16 + quad * 4 + r;
                        float rr = fast_sigmoid(arz[nt][rt][r]);
                        float zz = fast_sigmoid(arz[2 + nt][rt][r]);
                        float nn =
                            fast_tanh(axn[nt][rt][r] + rr * ahn[nt][rt][r]);
                        float hold = bf2f(h1s[row * 264 + col]);
                        h1s[row * 264 + col] = f2bf((1.f - zz) * nn + zz * hold);
                    }
            }
        }
        barrier_lgkm();  // B3: h1' visible

        // ---------------- delta = h1' @ ow.T + ob ; cumsum -> out
        {
            int brow = tid >> 3, p = tid & 7;
            float d0 = 0.f, d1 = 0.f;
#pragma unroll
            for (int j = 0; j < 4; ++j) {
                int cb = ((p + brow) & 7) * 8 + j * 64;
                bf16x8 hv8 = *reinterpret_cast<const bf16x8*>(h1s + brow * 264 + cb);
#pragma unroll
                for (int i = 0; i < 8; ++i) {
                    float hv = bf2f(hv8[i]);
                    d0 += hv * owl[cb + i];
                    d1 += hv * owl[256 + cb + i];
                }
            }
            d0 += __shfl_xor(d0, 1); d0 += __shfl_xor(d0, 2); d0 += __shfl_xor(d0, 4);
            d1 += __shfl_xor(d1, 1); d1 += __shfl_xor(d1, 2); d1 += __shfl_xor(d1, 4);
            d0 += ob0v;
            d1 += ob1v;
            if (p == 0) {
                cum0 += d0;
                cum1 += d1;
                size_t o = (((size_t)(b0 + brow) * 3 + m) * (size_t)T + st) * 2;
                out[o] = cum0;
                out[o + 1] = cum1;
                posD[brow * 2] = d0;
                posD[brow * 2 + 1] = d1;
            }
        }
        barrier_lgkm();  // B4: posD ready
    }
    asm volatile("s_waitcnt vmcnt(0)" ::: "memory");  // drain tail DMAs
}

extern "C" void kernel_launch(void* const* d_in, const int* in_sizes, int n_in,
                              void* d_out, int out_size, void* d_ws, size_t ws_size,
                              hipStream_t stream) {
    const float* context = (const float*)d_in[0];
    const float* mp_w1 = (const float*)d_in[1];
    const float* mp_b1 = (const float*)d_in[2];
    const float* mp_w2 = (const float*)d_in[3];
    const float* mp_b2 = (const float*)d_in[4];
    const float* w_ih0 = (const float*)d_in[5];
    const float* w_hh0 = (const float*)d_in[6];
    const float* b_ih0 = (const float*)d_in[7];
    const float* b_hh0 = (const float*)d_in[8];
    const float* w_ih1 = (const float*)d_in[9];
    const float* w_hh1 = (const float*)d_in[10];
    const float* b_ih1 = (const float*)d_in[11];
    const float* b_hh1 = (const float*)d_in[12];
    const float* out_w = (const float*)d_in[13];
    const float* out_b = (const float*)d_in[14];
    const int* pT = (const int*)d_in[15];
    float* out = (float*)d_out;
    short* ws = (short*)d_ws;

    const int B = in_sizes[0] / 256;                      // 4096
    const int ntiles = B / 64;                            // 64
    const long probs_off = (long)out_size - (long)B * 3;

    prep_kernel<<<4608, 64, 0, stream>>>(w_ih0, w_hh0, w_ih1, w_hh1, ws);
    modeprobs_kernel<<<B / 64, 256, 0, stream>>>(context, mp_w1, mp_b1, mp_w2,
                                                 mp_b2, out, probs_off);
    const int nslots = (ntiles + 1) / 2;
    decoder_kernel<<<8 * nslots, 512, 0, stream>>>(
        context, w_ih0, b_ih0, b_hh0, b_ih1, b_hh1, out_w, out_b, ws, out, pT,
        ntiles);
}